// Round 1
// baseline (1792.769 us; speedup 1.0000x reference)
//
#include <hip/hip_runtime.h>

// ======================================================================
// ALSH-VGG forward, fp32, NHWC internal layout.
// Conv = implicit GEMM: 64x64 tile, BK=32 chunks over (tap, ci),
// LDS A[k][m] / B[k][n] (pad 68), 4x4 outputs/thread, 256 threads.
// BN: pass1 per-channel sum/sumsq (atomics), pass2 affine+relu(+pool).
// ======================================================================

#define U_CONST 0.999f

// ---------- workspace layout (float offsets) ----------
constexpr size_t OFF_XT    = 0;          // 256*32*32*3 = 786432
constexpr size_t OFF_WT2   = 786432;     // 9*64*64
constexpr size_t OFF_WT3   = 823296;     // 9*64*128
constexpr size_t OFF_WT4   = 897024;     // 9*128*128
constexpr size_t OFF_WT5   = 1044480;    // 9*128*256
constexpr size_t OFF_WT6   = 1339392;    // 9*256*256
constexpr size_t OFF_STATS = 1929216;    // 7 * 512 floats (st1..st6, qstat)
constexpr size_t OFF_WSTAT = 1932800;    // 256*4 (sumsq, dot0, dot1, pad)
constexpr size_t OFF_MASK  = 1933824;    // 256
constexpr size_t OFF_FC7   = 1934080;    // 256*512
constexpr size_t OFF_FC8   = 2065152;    // 256*512
constexpr size_t OFF_BUFA  = 2196224;    // 16777216 floats (64MB)
constexpr size_t OFF_BUFB  = 18973440;   // 16777216 floats (64MB)
// total ~136.4 MB of d_ws

// ---------- layout transforms ----------
__global__ __launch_bounds__(256) void k_xform_x(const float* __restrict__ x,
                                                 float* __restrict__ xt) {
  int idx = blockIdx.x * 256 + threadIdx.x;          // 786432 total
  if (idx >= 256 * 3 * 1024) return;
  int c = idx % 3;
  int t = idx / 3;
  int s = t % 1024;
  int b = t / 1024;
  xt[idx] = x[(b * 3 + c) * 1024 + s];               // NCHW -> NHWC
}

__global__ __launch_bounds__(256) void k_xform_w(const float* __restrict__ w,
                                                 float* __restrict__ wt,
                                                 int CO, int CI) {
  int total = CO * CI * 9;
  for (int idx = blockIdx.x * 256 + threadIdx.x; idx < total;
       idx += gridDim.x * 256) {
    int co = idx % CO;
    int t = idx / CO;
    int ci = t % CI;
    int tap = t / CI;
    wt[idx] = w[(co * CI + ci) * 9 + tap];           // OIHW -> [tap][ci][co]
  }
}

// ---------- conv1 (CIN=3) : block = 2 image rows x 64 out-ch ----------
__global__ __launch_bounds__(256) void k_conv1(const float* __restrict__ xt,
                                               const float* __restrict__ w1,
                                               const float* __restrict__ b1,
                                               float* __restrict__ y) {
  __shared__ float Ins[4 * 34 * 3];   // rows y0-1..y0+2, x -1..32, ci 0..2
  __shared__ float Ws[27 * 64];       // [(tap*3+ci)*64 + co]
  int tid = threadIdx.x;
  int m0 = blockIdx.x * 64;
  int b = m0 >> 10;
  int y0 = (m0 & 1023) >> 5;

  for (int i = tid; i < 27 * 64; i += 256) {
    int co = i & 63;
    int t = i >> 6;
    int ci = t % 3;
    int tap = t / 3;
    Ws[i] = w1[co * 27 + ci * 9 + tap];
  }
  for (int i = tid; i < 4 * 34 * 3; i += 256) {
    int ci = i % 3;
    int t = i / 3;
    int xx = t % 34;
    int yy = t / 34;
    int gy = y0 - 1 + yy;
    int gx = xx - 1;
    float v = 0.f;
    if ((unsigned)gy < 32u && (unsigned)gx < 32u)
      v = xt[((b * 32 + gy) * 32 + gx) * 3 + ci];
    Ins[i] = v;
  }
  __syncthreads();

  int tr = tid >> 4, tc = tid & 15;
  float acc[4][4] = {};
#pragma unroll
  for (int tap = 0; tap < 9; tap++) {
    int dy = tap / 3, dx = tap % 3;
#pragma unroll
    for (int ci = 0; ci < 3; ci++) {
      float4 wv = *(const float4*)&Ws[(tap * 3 + ci) * 64 + tc * 4];
#pragma unroll
      for (int i = 0; i < 4; i++) {
        int r = tr * 4 + i;
        int yy = (r >> 5) + dy;
        int xx = (r & 31) + dx;
        float a = Ins[(yy * 34 + xx) * 3 + ci];
        acc[i][0] += a * wv.x;
        acc[i][1] += a * wv.y;
        acc[i][2] += a * wv.z;
        acc[i][3] += a * wv.w;
      }
    }
  }
  float4 bb = *(const float4*)&b1[tc * 4];
#pragma unroll
  for (int i = 0; i < 4; i++) {
    size_t r = (size_t)(m0 + tr * 4 + i);
    float4 o;
    o.x = acc[i][0] + bb.x;
    o.y = acc[i][1] + bb.y;
    o.z = acc[i][2] + bb.z;
    o.w = acc[i][3] + bb.w;
    *(float4*)&y[r * 64 + tc * 4] = o;
  }
}

// ---------- generic 3x3 conv, implicit GEMM ----------
template <int CIN, int COUT, int H, int W, bool MASKED>
__global__ __launch_bounds__(256) void k_conv(const float* __restrict__ in,
                                              const float* __restrict__ wt,
                                              const float* __restrict__ bias,
                                              const float* __restrict__ mask,
                                              float* __restrict__ out) {
  __shared__ float As[32][68];   // [k][m]
  __shared__ float Bs[32][68];   // [k][n]
  int tid = threadIdx.x;
  int m0 = blockIdx.x * 64;
  int n0 = blockIdx.y * 64;
  // A loader: row = tid/4, channel-quads lq and lq+4
  int lrow = tid >> 2, lq = tid & 3;
  int m = m0 + lrow;
  int lb = m / (H * W);
  int rem = m % (H * W);
  int ly = rem / W;
  int lx = rem % W;
  // B loader: k = tid/8, n-quads lq2 and lq2+8
  int lk = tid >> 3, lq2 = tid & 7;
  int tr = tid >> 4, tc = tid & 15;
  float acc[4][4] = {};

#pragma unroll 1
  for (int tap = 0; tap < 9; tap++) {
    int dy = tap / 3 - 1, dx = tap % 3 - 1;
    int yy = ly + dy, xx = lx + dx;
    bool valid = ((unsigned)yy < (unsigned)H) && ((unsigned)xx < (unsigned)W);
    const float* src = in + ((size_t)(lb * H + yy) * W + xx) * CIN;
    const float* wsrc = wt + (size_t)tap * CIN * COUT;
#pragma unroll 1
    for (int c0 = 0; c0 < CIN; c0 += 32) {
      float4 va0 = make_float4(0.f, 0.f, 0.f, 0.f), va1 = va0;
      if (valid) {
        va0 = *(const float4*)(src + c0 + lq * 4);
        va1 = *(const float4*)(src + c0 + lq * 4 + 16);
      }
      float4 vb0 = *(const float4*)(wsrc + (size_t)(c0 + lk) * COUT + n0 + lq2 * 4);
      float4 vb1 = *(const float4*)(wsrc + (size_t)(c0 + lk) * COUT + n0 + lq2 * 4 + 32);
      __syncthreads();
      As[lq * 4 + 0][lrow] = va0.x;
      As[lq * 4 + 1][lrow] = va0.y;
      As[lq * 4 + 2][lrow] = va0.z;
      As[lq * 4 + 3][lrow] = va0.w;
      As[lq * 4 + 16][lrow] = va1.x;
      As[lq * 4 + 17][lrow] = va1.y;
      As[lq * 4 + 18][lrow] = va1.z;
      As[lq * 4 + 19][lrow] = va1.w;
      *(float4*)&Bs[lk][lq2 * 4] = vb0;
      *(float4*)&Bs[lk][lq2 * 4 + 32] = vb1;
      __syncthreads();
#pragma unroll
      for (int k = 0; k < 32; k++) {
        float4 av = *(const float4*)&As[k][tr * 4];
        float4 bv = *(const float4*)&Bs[k][tc * 4];
        acc[0][0] += av.x * bv.x; acc[0][1] += av.x * bv.y;
        acc[0][2] += av.x * bv.z; acc[0][3] += av.x * bv.w;
        acc[1][0] += av.y * bv.x; acc[1][1] += av.y * bv.y;
        acc[1][2] += av.y * bv.z; acc[1][3] += av.y * bv.w;
        acc[2][0] += av.z * bv.x; acc[2][1] += av.z * bv.y;
        acc[2][2] += av.z * bv.z; acc[2][3] += av.z * bv.w;
        acc[3][0] += av.w * bv.x; acc[3][1] += av.w * bv.y;
        acc[3][2] += av.w * bv.z; acc[3][3] += av.w * bv.w;
      }
    }
  }
  float4 bb = *(const float4*)&bias[n0 + tc * 4];
  float4 mm = make_float4(1.f, 1.f, 1.f, 1.f);
  if (MASKED) mm = *(const float4*)&mask[n0 + tc * 4];
#pragma unroll
  for (int i = 0; i < 4; i++) {
    float4 o;
    o.x = acc[i][0] + bb.x;
    o.y = acc[i][1] + bb.y;
    o.z = acc[i][2] + bb.z;
    o.w = acc[i][3] + bb.w;
    if (MASKED) { o.x *= mm.x; o.y *= mm.y; o.z *= mm.z; o.w *= mm.w; }
    *(float4*)&out[(size_t)(m0 + tr * 4 + i) * COUT + n0 + tc * 4] = o;
  }
}

// ---------- per-channel sum/sumsq (NHWC, E = ROWS*C, power of 2) ----------
template <int C>
__global__ __launch_bounds__(256) void k_bnstat(const float* __restrict__ y,
                                                size_t E,
                                                float* __restrict__ stats) {
  size_t chunk = E >> 8;                     // grid is 256 blocks
  size_t base = (size_t)blockIdx.x * chunk;
  int tid = threadIdx.x;
  float s = 0.f, ss = 0.f;
  for (size_t i = base + tid; i < base + chunk; i += 256) {
    float v = y[i];
    s += v;
    ss += v * v;
  }
  __shared__ float rs[256], rss[256];
  rs[tid] = s;
  rss[tid] = ss;
  __syncthreads();
  if (tid < C) {
    for (int o = tid + C; o < 256; o += C) {
      s += rs[o];
      ss += rss[o];
    }
    atomicAdd(&stats[tid * 2], s);
    atomicAdd(&stats[tid * 2 + 1], ss);
  }
}

// ---------- affine+relu in place ----------
template <int C>
__global__ __launch_bounds__(256) void k_bnrelu(float* __restrict__ y, size_t E,
                                                float invN,
                                                const float* __restrict__ stats,
                                                const float* __restrict__ g,
                                                const float* __restrict__ be) {
  __shared__ float sA[C], sB[C];
  int tid = threadIdx.x;
  if (tid < C) {
    float mu = stats[tid * 2] * invN;
    float var = stats[tid * 2 + 1] * invN - mu * mu;
    float sc = g[tid] * rsqrtf(var + 1e-5f);
    sA[tid] = sc;
    sB[tid] = be[tid] - mu * sc;
  }
  __syncthreads();
  for (size_t i = (size_t)blockIdx.x * 256 + tid; i < E;
       i += (size_t)gridDim.x * 256) {
    int c = (int)(i & (C - 1));
    float v = y[i] * sA[c] + sB[c];
    y[i] = v > 0.f ? v : 0.f;
  }
}

// ---------- affine+relu + 2x2 maxpool ----------
template <int C, int H, int W, bool NCHW_OUT>
__global__ __launch_bounds__(256) void k_bnrelupool(
    const float* __restrict__ y, float invN, const float* __restrict__ stats,
    const float* __restrict__ g, const float* __restrict__ be,
    float* __restrict__ out) {
  __shared__ float sA[C], sB[C];
  int tid = threadIdx.x;
  if (tid < C) {
    float mu = stats[tid * 2] * invN;
    float var = stats[tid * 2 + 1] * invN - mu * mu;
    float sc = g[tid] * rsqrtf(var + 1e-5f);
    sA[tid] = sc;
    sB[tid] = be[tid] - mu * sc;
  }
  __syncthreads();
  constexpr int HO = H / 2, WO = W / 2;
  size_t E = (size_t)256 * HO * WO * C;
  for (size_t i = (size_t)blockIdx.x * 256 + tid; i < E;
       i += (size_t)gridDim.x * 256) {
    int c = (int)(i & (C - 1));
    size_t t = i / C;
    int px = (int)(t % WO);
    t /= WO;
    int py = (int)(t % HO);
    int b = (int)(t / HO);
    const float* p = y + (((size_t)(b * H + 2 * py) * W + 2 * px) * C + c);
    float a_ = sA[c], b_ = sB[c];
    float v0 = fmaxf(p[0] * a_ + b_, 0.f);
    float v1 = fmaxf(p[C] * a_ + b_, 0.f);
    float v2 = fmaxf(p[(size_t)W * C] * a_ + b_, 0.f);
    float v3 = fmaxf(p[(size_t)W * C + C] * a_ + b_, 0.f);
    float mx = fmaxf(fmaxf(v0, v1), fmaxf(v2, v3));
    if (NCHW_OUT)
      out[((size_t)b * C + c) * (HO * WO) + py * WO + px] = mx;
    else
      out[i] = mx;
  }
}

// ---------- FC GEMM: out(256,N) = a(256,K) @ w(N,K)^T + bias ----------
template <int K, int N>
__global__ __launch_bounds__(256) void k_fc(const float* __restrict__ a,
                                            const float* __restrict__ w,
                                            const float* __restrict__ bias,
                                            float* __restrict__ out) {
  __shared__ float As[32][68], Bs[32][68];
  int tid = threadIdx.x;
  int m0 = blockIdx.x * 64, n0 = blockIdx.y * 64;
  int lrow = tid >> 2, lq = tid & 3;
  int ln = tid & 63, kq = tid >> 6;
  int tr = tid >> 4, tc = tid & 15;
  float acc[4][4] = {};
  for (int c0 = 0; c0 < K; c0 += 32) {
    float4 va0 = *(const float4*)(a + (size_t)(m0 + lrow) * K + c0 + lq * 4);
    float4 va1 = *(const float4*)(a + (size_t)(m0 + lrow) * K + c0 + lq * 4 + 16);
    float4 vb0 = *(const float4*)(w + (size_t)(n0 + ln) * K + c0 + kq * 8);
    float4 vb1 = *(const float4*)(w + (size_t)(n0 + ln) * K + c0 + kq * 8 + 4);
    __syncthreads();
    As[lq * 4 + 0][lrow] = va0.x;
    As[lq * 4 + 1][lrow] = va0.y;
    As[lq * 4 + 2][lrow] = va0.z;
    As[lq * 4 + 3][lrow] = va0.w;
    As[lq * 4 + 16][lrow] = va1.x;
    As[lq * 4 + 17][lrow] = va1.y;
    As[lq * 4 + 18][lrow] = va1.z;
    As[lq * 4 + 19][lrow] = va1.w;
    Bs[kq * 8 + 0][ln] = vb0.x;
    Bs[kq * 8 + 1][ln] = vb0.y;
    Bs[kq * 8 + 2][ln] = vb0.z;
    Bs[kq * 8 + 3][ln] = vb0.w;
    Bs[kq * 8 + 4][ln] = vb1.x;
    Bs[kq * 8 + 5][ln] = vb1.y;
    Bs[kq * 8 + 6][ln] = vb1.z;
    Bs[kq * 8 + 7][ln] = vb1.w;
    __syncthreads();
#pragma unroll
    for (int k = 0; k < 32; k++) {
      float4 av = *(const float4*)&As[k][tr * 4];
      float4 bv = *(const float4*)&Bs[k][tc * 4];
      acc[0][0] += av.x * bv.x; acc[0][1] += av.x * bv.y;
      acc[0][2] += av.x * bv.z; acc[0][3] += av.x * bv.w;
      acc[1][0] += av.y * bv.x; acc[1][1] += av.y * bv.y;
      acc[1][2] += av.y * bv.z; acc[1][3] += av.y * bv.w;
      acc[2][0] += av.z * bv.x; acc[2][1] += av.z * bv.y;
      acc[2][2] += av.z * bv.z; acc[2][3] += av.z * bv.w;
      acc[3][0] += av.w * bv.x; acc[3][1] += av.w * bv.y;
      acc[3][2] += av.w * bv.z; acc[3][3] += av.w * bv.w;
    }
  }
  float4 bb = *(const float4*)&bias[n0 + tc * 4];
#pragma unroll
  for (int i = 0; i < 4; i++) {
    float4 o;
    o.x = acc[i][0] + bb.x;
    o.y = acc[i][1] + bb.y;
    o.z = acc[i][2] + bb.z;
    o.w = acc[i][3] + bb.w;
    *(float4*)&out[(size_t)(m0 + tr * 4 + i) * N + n0 + tc * 4] = o;
  }
}

// ---------- BN1d (+relu) in place: each thread owns one column ----------
template <int N>
__global__ __launch_bounds__(256) void k_bn1drelu(float* __restrict__ x,
                                                  const float* __restrict__ g,
                                                  const float* __restrict__ be) {
  int c = blockIdx.x * 256 + threadIdx.x;
  if (c >= N) return;
  float s = 0.f, ss = 0.f;
  for (int r = 0; r < 256; r++) {
    float v = x[(size_t)r * N + c];
    s += v;
    ss += v * v;
  }
  float mu = s * (1.f / 256.f);
  float var = ss * (1.f / 256.f) - mu * mu;
  float sc = g[c] * rsqrtf(var + 1e-5f);
  float sh = be[c] - mu * sc;
  for (int r = 0; r < 256; r++) {
    float v = x[(size_t)r * N + c] * sc + sh;
    x[(size_t)r * N + c] = v > 0.f ? v : 0.f;
  }
}

// ---------- fc9: (256,512) @ (10,512)^T + b ----------
__global__ __launch_bounds__(256) void k_fc9(const float* __restrict__ a,
                                             const float* __restrict__ w,
                                             const float* __restrict__ bias,
                                             float* __restrict__ out) {
  int b = blockIdx.x, tid = threadIdx.x;
  int o = tid & 15, ch = tid >> 4;
  float s = 0.f;
  if (o < 10) {
    const float* ap = a + (size_t)b * 512 + ch * 32;
    const float* wp = w + (size_t)o * 512 + ch * 32;
#pragma unroll
    for (int k = 0; k < 32; k++) s += ap[k] * wp[k];
  }
  __shared__ float red[16][17];
  red[ch][o] = s;
  __syncthreads();
  if (tid < 10) {
    float t = bias[tid];
#pragma unroll
    for (int c2 = 0; c2 < 16; c2++) t += red[c2][tid];
    out[b * 10 + tid] = t;
  }
}

// ---------- ALSH: per-filter sumsq + hash dots ----------
__global__ __launch_bounds__(256) void k_w6stats(const float* __restrict__ w6,
                                                 const float* __restrict__ ha,
                                                 float* __restrict__ wstats) {
  int f = blockIdx.x, tid = threadIdx.x;
  const float* wp = w6 + (size_t)f * 2304;
  float ss = 0.f, d0 = 0.f, d1 = 0.f;
#pragma unroll
  for (int k = 0; k < 9; k++) {
    float v = wp[k * 256 + tid];
    ss += v * v;
    d0 += v * ha[k * 256 + tid];
    d1 += v * ha[2306 + k * 256 + tid];
  }
  for (int off = 32; off > 0; off >>= 1) {
    ss += __shfl_down(ss, off);
    d0 += __shfl_down(d0, off);
    d1 += __shfl_down(d1, off);
  }
  __shared__ float r[4][3];
  int wv = tid >> 6, ln = tid & 63;
  if (ln == 0) {
    r[wv][0] = ss;
    r[wv][1] = d0;
    r[wv][2] = d1;
  }
  __syncthreads();
  if (tid == 0) {
    float a0 = 0.f, a1 = 0.f, a2 = 0.f;
    for (int i = 0; i < 4; i++) {
      a0 += r[i][0];
      a1 += r[i][1];
      a2 += r[i][2];
    }
    wstats[f * 4 + 0] = a0;
    wstats[f * 4 + 1] = a1;
    wstats[f * 4 + 2] = a2;
  }
}

// ---------- ALSH: final mask (single block) ----------
__global__ __launch_bounds__(256) void k_mask(const float* __restrict__ wstats,
                                              const float* __restrict__ qstats,
                                              const float* __restrict__ ha,
                                              float invN,
                                              float* __restrict__ mask) {
  int tid = threadIdx.x;
  __shared__ float red[256];
  float n2 = wstats[tid * 4];
  red[tid] = n2;
  __syncthreads();
  for (int off = 128; off > 0; off >>= 1) {
    if (tid < off) red[tid] = fmaxf(red[tid], red[tid + off]);
    __syncthreads();
  }
  float maxn2 = red[0];
  // q-side dot (normalization is positive -> sign-preserving, skip it)
  float qm = qstats[tid * 2] * invN;
  float h0 = 0.f, h1 = 0.f;
#pragma unroll
  for (int k = 0; k < 9; k++) {
    h0 += ha[k * 256 + tid];
    h1 += ha[2306 + k * 256 + tid];
  }
  __shared__ float r0[256], r1[256];
  r0[tid] = qm * h0;
  r1[tid] = qm * h1;
  __syncthreads();
  for (int off = 128; off > 0; off >>= 1) {
    if (tid < off) {
      r0[tid] += r0[tid + off];
      r1[tid] += r1[tid + off];
    }
    __syncthreads();
  }
  float qd0 = r0[0], qd1 = r1[0];
  float s = U_CONST / sqrtf(maxn2);
  float ns2 = s * s * wstats[tid * 4];
  float v0 = s * wstats[tid * 4 + 1] + ns2 * ha[2304] + ns2 * ns2 * ha[2305];
  float v1 = s * wstats[tid * 4 + 2] + ns2 * ha[2306 + 2304] +
             ns2 * ns2 * ha[2306 + 2305];
  bool bf0 = v0 > 0.f, bf1 = v1 > 0.f;
  bool bq0 = qd0 > 0.f, bq1 = qd1 > 0.f;
  mask[tid] = (bf0 == bq0 && bf1 == bq1) ? 1.f : 0.f;
}

// ======================================================================
extern "C" void kernel_launch(void* const* d_in, const int* in_sizes, int n_in,
                              void* d_out, int out_size, void* d_ws,
                              size_t ws_size, hipStream_t stream) {
  (void)in_sizes; (void)n_in; (void)out_size; (void)ws_size;
  const float* x = (const float*)d_in[0];
  const float* w1 = (const float*)d_in[1];
  const float* b1 = (const float*)d_in[2];
  const float* g1 = (const float*)d_in[3];
  const float* be1 = (const float*)d_in[4];
  const float* w2 = (const float*)d_in[5];
  const float* b2 = (const float*)d_in[6];
  const float* g2 = (const float*)d_in[7];
  const float* be2 = (const float*)d_in[8];
  const float* w3 = (const float*)d_in[9];
  const float* b3 = (const float*)d_in[10];
  const float* g3 = (const float*)d_in[11];
  const float* be3 = (const float*)d_in[12];
  const float* w4 = (const float*)d_in[13];
  const float* b4 = (const float*)d_in[14];
  const float* g4 = (const float*)d_in[15];
  const float* be4 = (const float*)d_in[16];
  const float* w5 = (const float*)d_in[17];
  const float* b5 = (const float*)d_in[18];
  const float* g5 = (const float*)d_in[19];
  const float* be5 = (const float*)d_in[20];
  const float* w6 = (const float*)d_in[21];
  const float* b6 = (const float*)d_in[22];
  const float* g6 = (const float*)d_in[23];
  const float* be6 = (const float*)d_in[24];
  const float* hash_a = (const float*)d_in[25];
  const float* fc7_w = (const float*)d_in[26];
  const float* fc7_b = (const float*)d_in[27];
  const float* g7 = (const float*)d_in[28];
  const float* be7 = (const float*)d_in[29];
  const float* fc8_w = (const float*)d_in[30];
  const float* fc8_b = (const float*)d_in[31];
  const float* g8 = (const float*)d_in[32];
  const float* be8 = (const float*)d_in[33];
  const float* fc9_w = (const float*)d_in[34];
  const float* fc9_b = (const float*)d_in[35];

  float* ws = (float*)d_ws;
  float* outp = (float*)d_out;
  float* xt = ws + OFF_XT;
  float* wt2 = ws + OFF_WT2;
  float* wt3 = ws + OFF_WT3;
  float* wt4 = ws + OFF_WT4;
  float* wt5 = ws + OFF_WT5;
  float* wt6 = ws + OFF_WT6;
  float* stats = ws + OFF_STATS;     // st(i) = stats + i*512, qst = stats+3072
  float* wstats = ws + OFF_WSTAT;
  float* maskb = ws + OFF_MASK;
  float* fc7o = ws + OFF_FC7;
  float* fc8o = ws + OFF_FC8;
  float* bufA = ws + OFF_BUFA;
  float* bufB = ws + OFF_BUFB;

  hipMemsetAsync(stats, 0, 3584 * sizeof(float), stream);

  k_xform_x<<<3072, 256, 0, stream>>>(x, xt);
  k_xform_w<<<144, 256, 0, stream>>>(w2, wt2, 64, 64);
  k_xform_w<<<288, 256, 0, stream>>>(w3, wt3, 128, 64);
  k_xform_w<<<576, 256, 0, stream>>>(w4, wt4, 128, 128);
  k_xform_w<<<1152, 256, 0, stream>>>(w5, wt5, 256, 128);
  k_xform_w<<<2304, 256, 0, stream>>>(w6, wt6, 256, 256);
  k_w6stats<<<256, 256, 0, stream>>>(w6, hash_a, wstats);

  // ---- layer 1: conv(3->64) @32x32 ----
  k_conv1<<<4096, 256, 0, stream>>>(xt, w1, b1, bufA);
  k_bnstat<64><<<256, 256, 0, stream>>>(bufA, (size_t)16777216, stats + 0);
  k_bnrelu<64><<<2048, 256, 0, stream>>>(bufA, (size_t)16777216,
                                         1.f / 262144.f, stats + 0, g1, be1);
  // ---- layer 2: conv(64->64) @32x32, then pool -> 16x16 ----
  k_conv<64, 64, 32, 32, false><<<dim3(4096, 1), 256, 0, stream>>>(
      bufA, wt2, b2, nullptr, bufB);
  k_bnstat<64><<<256, 256, 0, stream>>>(bufB, (size_t)16777216, stats + 512);
  k_bnrelupool<64, 32, 32, false><<<2048, 256, 0, stream>>>(
      bufB, 1.f / 262144.f, stats + 512, g2, be2, bufA);
  // ---- layer 3: conv(64->128) @16x16 ----
  k_conv<64, 128, 16, 16, false><<<dim3(1024, 2), 256, 0, stream>>>(
      bufA, wt3, b3, nullptr, bufB);
  k_bnstat<128><<<256, 256, 0, stream>>>(bufB, (size_t)8388608, stats + 1024);
  k_bnrelu<128><<<2048, 256, 0, stream>>>(bufB, (size_t)8388608,
                                          1.f / 65536.f, stats + 1024, g3, be3);
  // ---- layer 4: conv(128->128) @16x16, pool -> 8x8 ----
  k_conv<128, 128, 16, 16, false><<<dim3(1024, 2), 256, 0, stream>>>(
      bufB, wt4, b4, nullptr, bufA);
  k_bnstat<128><<<256, 256, 0, stream>>>(bufA, (size_t)8388608, stats + 1536);
  k_bnrelupool<128, 16, 16, false><<<2048, 256, 0, stream>>>(
      bufA, 1.f / 65536.f, stats + 1536, g4, be4, bufB);
  // ---- layer 5: conv(128->256) @8x8 ----
  k_conv<128, 256, 8, 8, false><<<dim3(256, 4), 256, 0, stream>>>(
      bufB, wt5, b5, nullptr, bufA);
  k_bnstat<256><<<256, 256, 0, stream>>>(bufA, (size_t)4194304, stats + 2048);
  k_bnrelu<256><<<2048, 256, 0, stream>>>(bufA, (size_t)4194304,
                                          1.f / 16384.f, stats + 2048, g5, be5);
  // ---- ALSH mask from a5 ----
  k_bnstat<256><<<256, 256, 0, stream>>>(bufA, (size_t)4194304, stats + 3072);
  k_mask<<<1, 256, 0, stream>>>(wstats, stats + 3072, hash_a, 1.f / 16384.f,
                                maskb);
  // ---- layer 6: conv(256->256) @8x8 masked, pool -> 4x4, NCHW-flat ----
  k_conv<256, 256, 8, 8, true><<<dim3(256, 4), 256, 0, stream>>>(
      bufA, wt6, b6, maskb, bufB);
  k_bnstat<256><<<256, 256, 0, stream>>>(bufB, (size_t)4194304, stats + 2560);
  k_bnrelupool<256, 8, 8, true><<<2048, 256, 0, stream>>>(
      bufB, 1.f / 16384.f, stats + 2560, g6, be6, bufA);
  // ---- FC head ----
  k_fc<4096, 512><<<dim3(4, 8), 256, 0, stream>>>(bufA, fc7_w, fc7_b, fc7o);
  k_bn1drelu<512><<<2, 256, 0, stream>>>(fc7o, g7, be7);
  k_fc<512, 512><<<dim3(4, 8), 256, 0, stream>>>(fc7o, fc8_w, fc8_b, fc8o);
  k_bn1drelu<512><<<2, 256, 0, stream>>>(fc8o, g8, be8);
  k_fc9<<<256, 256, 0, stream>>>(fc8o, fc9_w, fc9_b, outp);
}